// Round 14
// baseline (264.131 us; speedup 1.0000x reference)
//
#include <hip/hip_runtime.h>

// RGCN layer: out[i] = relu( x[i]@root + bias + sum_r mean_{j in N_r(i)} x[j]@W[r] )
//
// Two-phase (linearity) + SOURCE COMPACTION:
//   H rows [0,N) = bf16(x@root + bias); then per rel r one row per USED src:
//   bf16(x[src]@W[r]).  out[i] = relu( H[i] + sum_e (1/c) * H[hidx_e] )
// pk2 packs hidx(20b) | r(3b); per-(dst,rel) counts rebuilt in gather_out via
// wave-parallel ballot histogram. Byte used-flags w/ plain stores (R21).
//
// R27: byte-identical RESUBMISSION of R26. R13 hard-crashed ("Aborted/core
// dumped" in pytest) -- distinct failure mode from both R9 (clean assertion)
// and R3/R6 (container-acquisition). Full audit of the sharding delta found
// no OOB / alignment / signature / rank-uniqueness bug; gemm_h+gather are
// byte-identical to the R11-passing kernel. Per the R6->R7 precedent,
// identical resubmission isolates infra vs kernel. PRE-COMMITTED: a second
// crash implicates the sharding empirically -> next round reverts to R11's
// unsharded erank and closes the experiment.
//
// R26: gemm_h v7 (proven 52.7us; occupancy chapter CLOSED -- v10's 2x
// occupancy only moved BW 3.8->4.03 TB/s while adding +24MB traffic; the
// gather+stream pattern caps ~4TB/s, v7 is within ~5% of that roofline).
// NEW in R26: 4-WAY SHARDED DEGREE ATOMICS (prep_hist bound by same-address
// RMW serialization, ~25ns/op measured R7):
//   erank[e] = atomicAdd(&deg4[dst*4 + (e&3)], 1)   (4x less contention)
//   scanA2 degree input = quad sum (int4 load)
//   edge_bin rank = subrank + prefix(quad, e&3)     (deg4 L2-hot, 1.6MB)
//
// gemm_h (v7, proven): 128 VGPR + 128 AGPR = exactly the 2-waves/SIMD
// budget -- do NOT add live registers. grid 512, 9-thread segment table,
// csrc dist-2 / XB dist-1 prefetch. asm cvt_pk OK at (256,2) ONLY (acc in
// VGPRs; R9/R10: asm "v" breaks when regalloc uses AGPRs at (256,4)).
// H row layout: u32 index (l16*4+p) = { lo: col 32p+l16, hi: +16 };
// gather_out decodes c0 = 32*(lane&3) + (lane>>2).

#define D 128

typedef __attribute__((ext_vector_type(8))) short bf16x8;
typedef __attribute__((ext_vector_type(4))) float f32x4;
typedef __attribute__((ext_vector_type(4))) unsigned u32x4;

__device__ inline unsigned short f32_to_bf16(float f) {
    unsigned u = __float_as_uint(f);
    return (unsigned short)((u + 0x7FFF + ((u >> 16) & 1)) >> 16);   // RNE
}
__device__ inline float bf_lo(unsigned u) { return __uint_as_float(u << 16); }
__device__ inline float bf_hi(unsigned u) { return __uint_as_float(u & 0xFFFF0000u); }

// ---------------------------------------------------------------------------
// zero_ws: deg4[4*(n_nodes+1)] and flags[4*nwords bytes] zero before hist.
// ---------------------------------------------------------------------------
__global__ __launch_bounds__(256) void zero_ws(
    int* __restrict__ deg4, unsigned* __restrict__ flagsW, int n4, int nwords)
{
    int i = blockIdx.x * 256 + threadIdx.x;
    if (i < n4) deg4[i] = 0;
    if (i < nwords) flagsW[i] = 0u;
}

// ---------------------------------------------------------------------------
// prep_hist: fused. Blocks [0,hist_blocks) do the edge histogram (atomic
// latency-bound; start first): 4-way-sharded degree atomicAdd (returns
// sub-rank) + used-flag PLAIN byte store (benign same-value race, no RMW).
// Blocks [hist_blocks,..) do XB/WT conversion (streaming BW-bound).
// ---------------------------------------------------------------------------
__global__ __launch_bounds__(256) void prep_hist(
    const float* __restrict__ x, const float* __restrict__ W,
    const float* __restrict__ root,
    const int* __restrict__ edge_index, const int* __restrict__ edge_type,
    unsigned* __restrict__ XB, unsigned short* __restrict__ WT,
    int* __restrict__ deg4, unsigned char* __restrict__ flags,
    int* __restrict__ erank,
    int nquads, int wt_total, int n_edges, int n_nodes, int n_rel,
    int hist_blocks)
{
    const int b = blockIdx.x;
    if (b < hist_blocks) {
        int e = b * 256 + threadIdx.x;
        if (e >= n_edges) return;
        int src = edge_index[e];
        int dst = edge_index[n_edges + e];
        int r   = edge_type[e];
        erank[e] = atomicAdd(&deg4[(dst << 2) | (e & 3)], 1);  // sub-rank
        flags[r * n_nodes + src] = 1;                // used flag (plain store)
        return;
    }
    int i = (b - hist_blocks) * 256 + threadIdx.x;
    if (i < nquads) {
        float4 v = ((const float4*)x)[i];
        unsigned w0 = (unsigned)f32_to_bf16(v.x) | ((unsigned)f32_to_bf16(v.y) << 16);
        unsigned w1 = (unsigned)f32_to_bf16(v.z) | ((unsigned)f32_to_bf16(v.w) << 16);
        ((uint2*)XB)[i] = make_uint2(w0, w1);
    }
    if (i < wt_total) {
        int seg = i >> 14, rem = i & 16383;
        int n = rem >> 7, k = rem & 127;
        float v = (seg == 0) ? root[k * D + n]
                             : W[(size_t)(seg - 1) * D * D + k * D + n];
        WT[i] = f32_to_bf16(v);
    }
}

// ---------------------------------------------------------------------------
// scanA2: fused block-level exclusive scans. Blocks [0,nAd): degree scan over
// quad-sums of deg4[nd quads]. Blocks [nAd,..): flag-byte scan over
// flagsW[nw] words (bytes are 0/1 -> popc(word) = set-byte count).
// Consumers: Sd(i) = tmpd[i]+offsd[i>>10];  Sw(i) = tmpw[i]+offsw[i>>10].
// ---------------------------------------------------------------------------
__global__ __launch_bounds__(1024) void scanA2(
    const int* __restrict__ deg4, const unsigned* __restrict__ flagsW,
    int* __restrict__ tmpd, int* __restrict__ partsd,
    int* __restrict__ tmpw, int* __restrict__ partsw,
    int nd, int nw, int nAd)
{
    __shared__ int buf[2][1024];
    const int tid = threadIdx.x;
    const bool isDeg = ((int)blockIdx.x < nAd);
    const int lb = isDeg ? blockIdx.x : (blockIdx.x - nAd);
    int i = lb * 1024 + tid;
    int v;
    if (isDeg) {
        if (i < nd) {
            int4 dq = ((const int4*)deg4)[i];
            v = dq.x + dq.y + dq.z + dq.w;
        } else v = 0;
    } else {
        v = (i < nw) ? (int)__popc(flagsW[i]) : 0;
    }
    buf[0][tid] = v;
    __syncthreads();
    int pi = 0;
    for (int off = 1; off < 1024; off <<= 1) {
        int t = buf[pi][tid] + ((tid >= off) ? buf[pi][tid - off] : 0);
        buf[1 - pi][tid] = t;
        pi = 1 - pi;
        __syncthreads();
    }
    if (isDeg) {
        if (i < nd) tmpd[i] = buf[pi][tid] - v;
        if (tid == 1023) partsd[lb] = buf[pi][1023];
    } else {
        if (i < nw) tmpw[i] = buf[pi][tid] - v;
        if (tid == 1023) partsw[lb] = buf[pi][1023];
    }
}

// scanB2: block 0 scans degree partials -> offsd; block 1 scans word partials
// -> offsw + totw (total compact rows).
__global__ __launch_bounds__(1024) void scanB2(
    const int* __restrict__ partsd, const int* __restrict__ partsw,
    int* __restrict__ offsd, int* __restrict__ offsw,
    int* __restrict__ totw, int npd, int npw)
{
    __shared__ int buf[2][1024];
    const int t = threadIdx.x;
    const bool w = (blockIdx.x == 1);
    const int np = w ? npw : npd;
    int v = (t < np) ? (w ? partsw[t] : partsd[t]) : 0;
    buf[0][t] = v;
    __syncthreads();
    int pi = 0;
    for (int off = 1; off < 1024; off <<= 1) {
        int s = buf[pi][t] + ((t >= off) ? buf[pi][t - off] : 0);
        buf[1 - pi][t] = s;
        pi = 1 - pi;
        __syncthreads();
    }
    if (t < np) { if (w) offsw[t] = buf[pi][t] - v; else offsd[t] = buf[pi][t] - v; }
    if (w && t == 0) totw[0] = buf[pi][1023];
}

// ---------------------------------------------------------------------------
// edge_bin: CSR-place each edge at Sd(dst) + prefix(quad,slot) + subrank
// (no atomics); pack hidx|r; compact index from the word scan + intra-word
// byte popcount (flags/tmpw/offsw/deg4 ~3.2MB total -> L2-hot).
// ---------------------------------------------------------------------------
__global__ __launch_bounds__(256) void edge_bin(
    const int* __restrict__ edge_index, const int* __restrict__ edge_type,
    const int* __restrict__ tmpd, const int* __restrict__ offsd,
    const int* __restrict__ tmpw, const int* __restrict__ offsw,
    const unsigned* __restrict__ flagsW, const int* __restrict__ deg4,
    const int* __restrict__ erank,
    unsigned* __restrict__ pk2, int* __restrict__ csrc,
    int n_edges, int n_nodes, int n_rel)
{
    int e = blockIdx.x * 256 + threadIdx.x;
    if (e >= n_edges) return;
    int src = edge_index[e];
    int dst = edge_index[n_edges + e];
    int r   = edge_type[e];
    int4 dq = ((const int4*)deg4)[dst];
    int slot = e & 3;
    int rank = erank[e]
             + ((slot > 0) ? dq.x : 0)
             + ((slot > 1) ? dq.y : 0)
             + ((slot > 2) ? dq.z : 0);
    int pos = tmpd[dst] + offsd[dst >> 10] + rank;
    int gi  = r * n_nodes + src;
    int w   = gi >> 2;
    unsigned bw = flagsW[w];
    int cidx = tmpw[w] + offsw[w >> 10]
             + (int)__popc(bw & ((1u << (8 * (gi & 3))) - 1u));
    int hidx = n_nodes + cidx;                        // < 2^20
    pk2[pos] = (unsigned)hidx | ((unsigned)r << 20);
    csrc[cidx] = src;                                 // same-value race: benign
}

// ---------------------------------------------------------------------------
// Phase 1 (v7 pipeline, proven): flat-balanced H GEMM, register->global
// epilogue, 3-stage software pipeline: tile t computes while XB(t+1) loads
// (node index already resident from one iteration ago) and csrc(t+2) loads.
// grid (512, 1) -- 16 iters/block, 2 resident blocks/CU. Segment table built
// by 9 threads in parallel from the word scan. B-frags register/AGPR
// resident, reloaded only at segment boundaries (<=2 per block). 128 VGPR +
// ~128 AGPR = exactly the 2-waves/SIMD budget -- do NOT add live registers.
// ---------------------------------------------------------------------------
__global__ __launch_bounds__(256, 2) void gemm_h(
    const unsigned* __restrict__ XB, const unsigned short* __restrict__ WT,
    const float* __restrict__ bias, const int* __restrict__ csrc,
    const int* __restrict__ tmpw, const int* __restrict__ offsw,
    const int* __restrict__ totw, unsigned short* __restrict__ H,
    int n_nodes, int n_rel)
{
    __shared__ int s_end[9];     // cumulative flat-tile end per seg
    __shared__ int s_cnt[9];     // row count per seg
    __shared__ int s_S0[9];      // csrc base per seg
    __shared__ int s_base[9];    // H base row per seg

    const int tid  = threadIdx.x;
    const int wave = tid >> 6;
    const int lane = tid & 63;
    const int l16  = lane & 15;
    const int quad = lane >> 4;
    const int row_off = wave * 16 + l16;
    const int cq8  = quad * 8;

    // segment table: 9 threads in parallel, then 9-element prefix by thread 0.
    if (tid <= n_rel) {
        const int s = tid;
        int cnt, S0 = 0, base;
        if (s == 0) { cnt = n_nodes; base = 0; }
        else {
            int r = s - 1;
            const int wpr = n_nodes >> 2;            // flag words per rel
            int w0 = r * wpr;
            S0 = tmpw[w0] + offsw[w0 >> 10];
            int S1;
            if (r == n_rel - 1) S1 = totw[0];
            else { int w1 = w0 + wpr; S1 = tmpw[w1] + offsw[w1 >> 10]; }
            cnt = S1 - S0;
            base = n_nodes + S0;
        }
        s_cnt[s] = cnt; s_S0[s] = S0; s_base[s] = base;
        s_end[s] = (cnt + 63) >> 6;              // per-seg tile count (pre-prefix)
    }
    __syncthreads();
    if (tid == 0) {
        int acc = 0;
        for (int s = 0; s <= n_rel; ++s) { acc += s_end[s]; s_end[s] = acc; }
    }
    __syncthreads();

    const int nflat = s_end[n_rel];
    const int chunk = (nflat + gridDim.x - 1) / gridDim.x;
    const int ft0 = blockIdx.x * chunk;
    int ft1 = ft0 + chunk; if (ft1 > nflat) ft1 = nflat;
    if (ft0 >= ft1) return;

    auto resolve = [&](int ft, int& seg, int& lt) {
        int s = 0;
        while (ft >= s_end[s]) ++s;
        seg = s;
        lt = ft - (s ? s_end[s - 1] : 0);
    };
    auto load_node = [&](int seg, int lt) -> int {
        int lr = lt * 64 + row_off;
        if (lr >= s_cnt[seg]) return 0;
        return (seg == 0) ? lr : csrc[s_S0[seg] + lr];
    };
    auto load_af = [&](int seg, int lt, int node, bf16x8* fr) {
        int lr = lt * 64 + row_off;
        bool v = (lr < s_cnt[seg]);
        const unsigned short* xr = (const unsigned short*)XB + (size_t)node * D + cq8;
#pragma unroll
        for (int kc = 0; kc < 4; ++kc)
            fr[kc] = v ? *(const bf16x8*)(xr + kc * 32)
                       : (bf16x8){0, 0, 0, 0, 0, 0, 0, 0};
    };

    bf16x8 bfr[8][4];
    float bv[8];
    int cur_seg = -1;

    // ---- pipeline prologue ----
    int segA, ltA;
    resolve(ft0, segA, ltA);
    bf16x8 af[4];
    {
        int nodeA = load_node(segA, ltA);
        load_af(segA, ltA, nodeA, af);
    }
    int segB = 0, ltB = 0, nodeB = 0;
    if (ft0 + 1 < ft1) {
        resolve(ft0 + 1, segB, ltB);
        nodeB = load_node(segB, ltB);
    }

    for (int ft = ft0; ft < ft1; ++ft) {
        const int seg = segA, lt = ltA;
        const bool haveN  = (ft + 1 < ft1);
        const bool haveN2 = (ft + 2 < ft1);

        // stage 3: issue csrc for t+2 (completes during next iteration)
        int segC = 0, ltC = 0, nodeC = 0;
        if (haveN2) {
            resolve(ft + 2, segC, ltC);
            nodeC = load_node(segC, ltC);
        }

        // stage 2: issue XB gathers for t+1 (nodeB loaded one iteration ago)
        bf16x8 afn[4];
        if (haveN) load_af(segB, ltB, nodeB, afn);

        // (re)load B-frags + bias at segment boundary (<=2 per block)
        if (seg != cur_seg) {
            const unsigned short* Wseg = WT + (size_t)seg * D * D;
#pragma unroll
            for (int nt = 0; nt < 8; ++nt) {
                const unsigned short* bp = Wseg + (size_t)(nt * 16 + l16) * D + cq8;
#pragma unroll
                for (int kc = 0; kc < 4; ++kc)
                    bfr[nt][kc] = *(const bf16x8*)(bp + kc * 32);
                bv[nt] = (seg == 0) ? bias[nt * 16 + l16] : 0.f;
            }
            cur_seg = seg;
        }

        // stage 1: compute tile t (bias folded into MFMA C-in; same f32 math)
        f32x4 acc[8];
#pragma unroll
        for (int nt = 0; nt < 8; ++nt) {
            acc[nt] = (f32x4){bv[nt], bv[nt], bv[nt], bv[nt]};
#pragma unroll
            for (int kc = 0; kc < 4; ++kc)
                acc[nt] = __builtin_amdgcn_mfma_f32_16x16x32_bf16(
                    af[kc], bfr[nt][kc], acc[nt], 0, 0, 0);
        }

        // Epilogue: hardware RNE pack (col 32p+l16, col 32p+l16+16) -> u32,
        // one dwordx4 per owned row. Coalesces as 4x256B segments per inst.
        // (inline-asm cvt_pk is safe HERE: at (256,2) acc stays in VGPRs --
        //  passed twice. Do not reuse at (256,4).)
        {
            const int rbase = lt * 64 + wave * 16 + quad * 4;
            unsigned short* Hrow =
                H + (size_t)(s_base[seg] + rbase) * D + (size_t)l16 * 8;
#pragma unroll
            for (int reg = 0; reg < 4; ++reg) {
                if (rbase + reg < s_cnt[seg]) {
                    u32x4 w;
#pragma unroll
                    for (int p = 0; p < 4; ++p) {
                        unsigned r;
                        asm("v_cvt_pk_bf16_f32 %0, %1, %2"
                            : "=v"(r)
                            : "v"(acc[2 * p][reg]), "v"(acc[2 * p + 1][reg]));
                        w[p] = r;
                    }
                    *(u32x4*)(Hrow + (size_t)reg * D) = w;
                }
            }
        }

        // rotate pipeline state
        if (haveN) {
            segA = segB; ltA = ltB;
#pragma unroll
            for (int kc = 0; kc < 4; ++kc) af[kc] = afn[kc];
        }
        if (haveN2) { segB = segC; ltB = ltC; nodeB = nodeC; }
    }
}

// ---------------------------------------------------------------------------
// Phase 2: one wave per dst node; dst made explicitly wave-uniform so
// pk2/bounds go through scalar loads; per-lane work = H load + 2 unpack +
// 2 FMA per edge. Per-(dst,rel) counts via wave-parallel ballot histogram
// (one coalesced pk2 vector load, 8 ballots -> packed 8-bit fields in two
// u32s; scalar fallback for degree > 64). 1/c via v_rcp (~1 ulp).
// H columns are permuted (see gemm_h): lane j's u32 holds cols
// c0 = 32*(j&3) + (j>>2) and c0+16 -> two dword stores at the end.
// ---------------------------------------------------------------------------
__global__ __launch_bounds__(256) void gather_out(
    const unsigned short* __restrict__ H, const unsigned* __restrict__ pk2,
    const int* __restrict__ tmpd, const int* __restrict__ offsd,
    float* __restrict__ out, int n_nodes)
{
    int dst = (blockIdx.x * 256 + threadIdx.x) >> 6;
    const int lane = threadIdx.x & 63;
    if (dst >= n_nodes) return;
    dst = __builtin_amdgcn_readfirstlane(dst);   // wave-uniform by construction

    const unsigned* HH = (const unsigned*)H;
    unsigned u0 = HH[(size_t)dst * 64 + lane];   // root+bias row
    float a0 = bf_lo(u0), a1 = bf_hi(u0);

    const int e0 = tmpd[dst] + offsd[dst >> 10];
    const int e1 = tmpd[dst + 1] + offsd[(dst + 1) >> 10];
    const int d  = e1 - e0;

    // per-rel counts (8x 8-bit fields in two u32s)
    unsigned acc0 = 0, acc1 = 0;
    if (d <= 64) {
        const bool valid = lane < d;
        unsigned p = valid ? pk2[e0 + lane] : 0u;
        unsigned r = (p >> 20) & 7u;
#pragma unroll
        for (int rr = 0; rr < 8; ++rr) {
            unsigned long long m = __ballot(valid && (r == (unsigned)rr));
            unsigned cnt = (unsigned)__popcll(m);
            if (rr < 4) acc0 |= cnt << (rr * 8);
            else        acc1 |= cnt << ((rr - 4) * 8);
        }
    } else {
        for (int e = e0; e < e1; ++e) {
            unsigned p = pk2[e];
            unsigned r = (p >> 20) & 7u;
            unsigned add = 1u << ((r & 3u) * 8u);
            if (r & 4u) acc1 += add; else acc0 += add;
        }
    }

    for (int base = e0; base < e1; base += 8) {
        float al[8];
        const unsigned* hp[8];
#pragma unroll
        for (int j = 0; j < 8; ++j) {
            int e = base + j;
            bool ok = (e < e1);
            unsigned p = ok ? pk2[e] : 0u;       // uniform address -> s_load
            unsigned r = (p >> 20) & 7u;
            unsigned cnt = (((r & 4u) ? acc1 : acc0) >> ((r & 3u) * 8u)) & 255u;
            al[j] = ok ? __builtin_amdgcn_rcpf((float)cnt) : 0.f;
            hp[j] = HH + (size_t)(p & 0xFFFFFu) * 64;
        }
        unsigned hv[8];
#pragma unroll
        for (int j = 0; j < 8; ++j) hv[j] = hp[j][lane];
#pragma unroll
        for (int j = 0; j < 8; ++j) {
            a0 += al[j] * bf_lo(hv[j]);
            a1 += al[j] * bf_hi(hv[j]);
        }
    }

    const int c0 = ((lane & 3) << 5) + (lane >> 2);
    float* orow = out + (size_t)dst * D;
    orow[c0]      = fmaxf(a0, 0.f);
    orow[c0 + 16] = fmaxf(a1, 0.f);
}

extern "C" void kernel_launch(void* const* d_in, const int* in_sizes, int n_in,
                              void* d_out, int out_size, void* d_ws, size_t ws_size,
                              hipStream_t stream) {
    const float* x          = (const float*)d_in[0];
    const int*   edge_index = (const int*)d_in[1];
    const int*   edge_type  = (const int*)d_in[2];
    const float* W          = (const float*)d_in[3];
    const float* root       = (const float*)d_in[4];
    const float* bias       = (const float*)d_in[5];
    float* out = (float*)d_out;

    const int n_nodes = in_sizes[0] / D;          // 100000 (assumed %4==0)
    const int n_edges = in_sizes[2];              // 600000
    const int n_rel   = in_sizes[3] / (D * D);    // 8
    const int nsegs   = n_rel + 1;
    const int nwords  = (n_rel * n_nodes) >> 2;   // 200000 (800KB byte flags)
    const int n4      = (n_nodes + 1) * 4;        // sharded degree counters

    // ws layout (worst-case compact rows = n_rel*n_nodes)
    char* p = (char*)d_ws;
    auto alloc = [&](size_t bytes) {
        char* q = p; p += (bytes + 255) & ~(size_t)255; return q;
    };
    int* deg4   = (int*)alloc((size_t)n4 * 4);
    int* tmpd   = (int*)alloc((size_t)(n_nodes + 2) * 4);
    unsigned* flagsW = (unsigned*)alloc((size_t)nwords * 4);
    int* tmpw   = (int*)alloc((size_t)(nwords + 1) * 4);
    int* partsd = (int*)alloc(4096);
    int* partsw = (int*)alloc(4096);
    int* offsd  = (int*)alloc(4096);
    int* offsw  = (int*)alloc(4096);
    int* totw   = (int*)alloc(256);
    int* erank  = (int*)alloc((size_t)n_edges * 4);
    unsigned* pk2 = (unsigned*)alloc((size_t)n_edges * 4);
    unsigned* XB  = (unsigned*)alloc((size_t)n_nodes * (D / 2) * 4);
    unsigned short* WT = (unsigned short*)alloc((size_t)nsegs * D * D * 2);
    int* csrc   = (int*)alloc((size_t)n_edges * 4);
    unsigned short* H = (unsigned short*)p;       // worst (n_nodes + n_edges) rows

    const int nquads   = n_nodes * (D / 4);
    const int wt_total = nsegs * D * D;
    int conv_n = nquads;
    if (wt_total > conv_n) conv_n = wt_total;

    const int egrid = (n_edges + 255) / 256;
    const int conv_blocks = (conv_n + 255) / 256;
    const int nAd = (n_nodes + 1 + 1023) / 1024;  // 98
    const int nAw = (nwords + 1023) / 1024;       // 196

    int zero_n = n4;
    if (nwords > zero_n) zero_n = nwords;

    zero_ws<<<(zero_n + 255) / 256, 256, 0, stream>>>(
        deg4, flagsW, n4, nwords);
    prep_hist<<<egrid + conv_blocks, 256, 0, stream>>>(
        x, W, root, edge_index, edge_type, XB, WT, deg4,
        (unsigned char*)flagsW, erank,
        nquads, wt_total, n_edges, n_nodes, n_rel, egrid);
    scanA2<<<nAd + nAw, 1024, 0, stream>>>(
        deg4, flagsW, tmpd, partsd, tmpw, partsw, n_nodes + 1, nwords, nAd);
    scanB2<<<2, 1024, 0, stream>>>(partsd, partsw, offsd, offsw, totw, nAd, nAw);
    edge_bin<<<egrid, 256, 0, stream>>>(
        edge_index, edge_type, tmpd, offsd, tmpw, offsw, flagsW, deg4, erank,
        pk2, csrc, n_edges, n_nodes, n_rel);
    gemm_h<<<512, 256, 0, stream>>>(
        XB, WT, bias, csrc, tmpw, offsw, totw, H, n_nodes, n_rel);
    gather_out<<<(n_nodes + 3) / 4, 256, 0, stream>>>(
        H, pk2, tmpd, offsd, out, n_nodes);
}

// Round 15
// 257.569 us; speedup vs baseline: 1.0255x; 1.0255x over previous
//
#include <hip/hip_runtime.h>

// RGCN layer: out[i] = relu( x[i]@root + bias + sum_r mean_{j in N_r(i)} x[j]@W[r] )
//
// Two-phase (linearity) + SOURCE COMPACTION:
//   H rows [0,N) = bf16(x@root + bias); then per rel r one row per USED src:
//   bf16(x[src]@W[r]).  out[i] = relu( H[i] + sum_e (1/c) * H[hidx_e] )
// pk2 packs hidx(20b) | r(3b); per-(dst,rel) counts rebuilt in gather_out via
// wave-parallel ballot histogram. Byte used-flags w/ plain stores (R21).
//
// R28: REVERT to R11 (proven 257.8us) + zero_ws kernel replaced by ONE
// hipMemsetAsync (deg and flagsW made adjacent in ws; 1.2MB; graph-safe --
// the harness reset uses hipMemsetAsync itself).
// CLOSED chapters (do not reopen):
//  - gemm_h occupancy: v9 column-split = kx A-traffic (FETCH 66->250MB);
//    v10 B-in-LDS 2x-occupancy = +24MB L2 thrash + bank conflicts. v7's
//    201MB @ 3.8TB/s is within ~5% of the gather+stream pattern ceiling.
//  - atomic sharding (R14: 264us vs 257.8 -- 4x cache-line spread at the
//    coherence point + deg4 reads cost more than contention saved).
//  - atomicOr flags (R7: +15us; RMW COUNT is the cost, not footprint).
//  - asm "v"-constraint cvt_pk at (256,4) (R9: AGPR-allocated acc -> garbage;
//    safe at (256,2) only).
//
// gemm_h (v7, proven): 128 VGPR + 128 AGPR = exactly the 2-waves/SIMD
// budget -- do NOT add live registers. grid 512, 9-thread segment table,
// csrc dist-2 / XB dist-1 prefetch.
// H row layout: u32 index (l16*4+p) = { lo: col 32p+l16, hi: +16 };
// gather_out decodes c0 = 32*(lane&3) + (lane>>2).

#define D 128

typedef __attribute__((ext_vector_type(8))) short bf16x8;
typedef __attribute__((ext_vector_type(4))) float f32x4;
typedef __attribute__((ext_vector_type(4))) unsigned u32x4;

__device__ inline unsigned short f32_to_bf16(float f) {
    unsigned u = __float_as_uint(f);
    return (unsigned short)((u + 0x7FFF + ((u >> 16) & 1)) >> 16);   // RNE
}
__device__ inline float bf_lo(unsigned u) { return __uint_as_float(u << 16); }
__device__ inline float bf_hi(unsigned u) { return __uint_as_float(u & 0xFFFF0000u); }

// ---------------------------------------------------------------------------
// prep_hist: fused. Blocks [0,hist_blocks) do the edge histogram (atomic
// latency-bound; start first): degree atomicAdd (returns rank-in-dst) +
// used-flag PLAIN byte store (benign same-value race, no RMW).
// Blocks [hist_blocks,..) do XB/WT conversion (streaming BW-bound).
// ---------------------------------------------------------------------------
__global__ __launch_bounds__(256) void prep_hist(
    const float* __restrict__ x, const float* __restrict__ W,
    const float* __restrict__ root,
    const int* __restrict__ edge_index, const int* __restrict__ edge_type,
    unsigned* __restrict__ XB, unsigned short* __restrict__ WT,
    int* __restrict__ deg, unsigned char* __restrict__ flags,
    int* __restrict__ erank,
    int nquads, int wt_total, int n_edges, int n_nodes, int n_rel,
    int hist_blocks)
{
    const int b = blockIdx.x;
    if (b < hist_blocks) {
        int e = b * 256 + threadIdx.x;
        if (e >= n_edges) return;
        int src = edge_index[e];
        int dst = edge_index[n_edges + e];
        int r   = edge_type[e];
        erank[e] = atomicAdd(&deg[dst], 1);          // degree + rank-in-dst
        flags[r * n_nodes + src] = 1;                // used flag (plain store)
        return;
    }
    int i = (b - hist_blocks) * 256 + threadIdx.x;
    if (i < nquads) {
        float4 v = ((const float4*)x)[i];
        unsigned w0 = (unsigned)f32_to_bf16(v.x) | ((unsigned)f32_to_bf16(v.y) << 16);
        unsigned w1 = (unsigned)f32_to_bf16(v.z) | ((unsigned)f32_to_bf16(v.w) << 16);
        ((uint2*)XB)[i] = make_uint2(w0, w1);
    }
    if (i < wt_total) {
        int seg = i >> 14, rem = i & 16383;
        int n = rem >> 7, k = rem & 127;
        float v = (seg == 0) ? root[k * D + n]
                             : W[(size_t)(seg - 1) * D * D + k * D + n];
        WT[i] = f32_to_bf16(v);
    }
}

// ---------------------------------------------------------------------------
// scanA2: fused block-level exclusive scans. Blocks [0,nAd): degree scan over
// deg[nd]. Blocks [nAd,..): flag-byte scan over flagsW[nw] words (bytes are
// 0/1, so popc(word) = count of set bytes).
// Consumers: Sd(i) = tmpd[i]+offsd[i>>10];  Sw(i) = tmpw[i]+offsw[i>>10].
// ---------------------------------------------------------------------------
__global__ __launch_bounds__(1024) void scanA2(
    const int* __restrict__ deg, const unsigned* __restrict__ flagsW,
    int* __restrict__ tmpd, int* __restrict__ partsd,
    int* __restrict__ tmpw, int* __restrict__ partsw,
    int nd, int nw, int nAd)
{
    __shared__ int buf[2][1024];
    const int tid = threadIdx.x;
    const bool isDeg = ((int)blockIdx.x < nAd);
    const int lb = isDeg ? blockIdx.x : (blockIdx.x - nAd);
    int i = lb * 1024 + tid;
    int v;
    if (isDeg) v = (i < nd) ? deg[i] : 0;
    else       v = (i < nw) ? (int)__popc(flagsW[i]) : 0;
    buf[0][tid] = v;
    __syncthreads();
    int pi = 0;
    for (int off = 1; off < 1024; off <<= 1) {
        int t = buf[pi][tid] + ((tid >= off) ? buf[pi][tid - off] : 0);
        buf[1 - pi][tid] = t;
        pi = 1 - pi;
        __syncthreads();
    }
    if (isDeg) {
        if (i < nd) tmpd[i] = buf[pi][tid] - v;
        if (tid == 1023) partsd[lb] = buf[pi][1023];
    } else {
        if (i < nw) tmpw[i] = buf[pi][tid] - v;
        if (tid == 1023) partsw[lb] = buf[pi][1023];
    }
}

// scanB2: block 0 scans degree partials -> offsd; block 1 scans word partials
// -> offsw + totw (total compact rows).
__global__ __launch_bounds__(1024) void scanB2(
    const int* __restrict__ partsd, const int* __restrict__ partsw,
    int* __restrict__ offsd, int* __restrict__ offsw,
    int* __restrict__ totw, int npd, int npw)
{
    __shared__ int buf[2][1024];
    const int t = threadIdx.x;
    const bool w = (blockIdx.x == 1);
    const int np = w ? npw : npd;
    int v = (t < np) ? (w ? partsw[t] : partsd[t]) : 0;
    buf[0][t] = v;
    __syncthreads();
    int pi = 0;
    for (int off = 1; off < 1024; off <<= 1) {
        int s = buf[pi][t] + ((t >= off) ? buf[pi][t - off] : 0);
        buf[1 - pi][t] = s;
        pi = 1 - pi;
        __syncthreads();
    }
    if (t < np) { if (w) offsw[t] = buf[pi][t] - v; else offsd[t] = buf[pi][t] - v; }
    if (w && t == 0) totw[0] = buf[pi][1023];
}

// ---------------------------------------------------------------------------
// edge_bin: CSR-place each edge at Sd(dst)+rank (no atomics); pack hidx|r;
// compact index from the word scan + intra-word byte popcount (flags/tmpw/
// offsw are ~1.6MB total -> L2-hot). csrc same-value races: benign.
// ---------------------------------------------------------------------------
__global__ __launch_bounds__(256) void edge_bin(
    const int* __restrict__ edge_index, const int* __restrict__ edge_type,
    const int* __restrict__ tmpd, const int* __restrict__ offsd,
    const int* __restrict__ tmpw, const int* __restrict__ offsw,
    const unsigned* __restrict__ flagsW, const int* __restrict__ erank,
    unsigned* __restrict__ pk2, int* __restrict__ csrc,
    int n_edges, int n_nodes, int n_rel)
{
    int e = blockIdx.x * 256 + threadIdx.x;
    if (e >= n_edges) return;
    int src = edge_index[e];
    int dst = edge_index[n_edges + e];
    int r   = edge_type[e];
    int pos = tmpd[dst] + offsd[dst >> 10] + erank[e];
    int gi  = r * n_nodes + src;
    int w   = gi >> 2;
    unsigned bw = flagsW[w];
    int cidx = tmpw[w] + offsw[w >> 10]
             + (int)__popc(bw & ((1u << (8 * (gi & 3))) - 1u));
    int hidx = n_nodes + cidx;                        // < 2^20
    pk2[pos] = (unsigned)hidx | ((unsigned)r << 20);
    csrc[cidx] = src;                                 // same-value race: benign
}

// ---------------------------------------------------------------------------
// Phase 1 (v7 pipeline, proven): flat-balanced H GEMM, register->global
// epilogue, 3-stage software pipeline: tile t computes while XB(t+1) loads
// (node index already resident from one iteration ago) and csrc(t+2) loads.
// grid (512, 1) -- 16 iters/block, 2 resident blocks/CU. Segment table built
// by 9 threads in parallel from the word scan. B-frags register/AGPR
// resident, reloaded only at segment boundaries (<=2 per block). 128 VGPR +
// ~128 AGPR = exactly the 2-waves/SIMD budget -- do NOT add live registers.
// ---------------------------------------------------------------------------
__global__ __launch_bounds__(256, 2) void gemm_h(
    const unsigned* __restrict__ XB, const unsigned short* __restrict__ WT,
    const float* __restrict__ bias, const int* __restrict__ csrc,
    const int* __restrict__ tmpw, const int* __restrict__ offsw,
    const int* __restrict__ totw, unsigned short* __restrict__ H,
    int n_nodes, int n_rel)
{
    __shared__ int s_end[9];     // cumulative flat-tile end per seg
    __shared__ int s_cnt[9];     // row count per seg
    __shared__ int s_S0[9];      // csrc base per seg
    __shared__ int s_base[9];    // H base row per seg

    const int tid  = threadIdx.x;
    const int wave = tid >> 6;
    const int lane = tid & 63;
    const int l16  = lane & 15;
    const int quad = lane >> 4;
    const int row_off = wave * 16 + l16;
    const int cq8  = quad * 8;

    // segment table: 9 threads in parallel, then 9-element prefix by thread 0.
    if (tid <= n_rel) {
        const int s = tid;
        int cnt, S0 = 0, base;
        if (s == 0) { cnt = n_nodes; base = 0; }
        else {
            int r = s - 1;
            const int wpr = n_nodes >> 2;            // flag words per rel
            int w0 = r * wpr;
            S0 = tmpw[w0] + offsw[w0 >> 10];
            int S1;
            if (r == n_rel - 1) S1 = totw[0];
            else { int w1 = w0 + wpr; S1 = tmpw[w1] + offsw[w1 >> 10]; }
            cnt = S1 - S0;
            base = n_nodes + S0;
        }
        s_cnt[s] = cnt; s_S0[s] = S0; s_base[s] = base;
        s_end[s] = (cnt + 63) >> 6;              // per-seg tile count (pre-prefix)
    }
    __syncthreads();
    if (tid == 0) {
        int acc = 0;
        for (int s = 0; s <= n_rel; ++s) { acc += s_end[s]; s_end[s] = acc; }
    }
    __syncthreads();

    const int nflat = s_end[n_rel];
    const int chunk = (nflat + gridDim.x - 1) / gridDim.x;
    const int ft0 = blockIdx.x * chunk;
    int ft1 = ft0 + chunk; if (ft1 > nflat) ft1 = nflat;
    if (ft0 >= ft1) return;

    auto resolve = [&](int ft, int& seg, int& lt) {
        int s = 0;
        while (ft >= s_end[s]) ++s;
        seg = s;
        lt = ft - (s ? s_end[s - 1] : 0);
    };
    auto load_node = [&](int seg, int lt) -> int {
        int lr = lt * 64 + row_off;
        if (lr >= s_cnt[seg]) return 0;
        return (seg == 0) ? lr : csrc[s_S0[seg] + lr];
    };
    auto load_af = [&](int seg, int lt, int node, bf16x8* fr) {
        int lr = lt * 64 + row_off;
        bool v = (lr < s_cnt[seg]);
        const unsigned short* xr = (const unsigned short*)XB + (size_t)node * D + cq8;
#pragma unroll
        for (int kc = 0; kc < 4; ++kc)
            fr[kc] = v ? *(const bf16x8*)(xr + kc * 32)
                       : (bf16x8){0, 0, 0, 0, 0, 0, 0, 0};
    };

    bf16x8 bfr[8][4];
    float bv[8];
    int cur_seg = -1;

    // ---- pipeline prologue ----
    int segA, ltA;
    resolve(ft0, segA, ltA);
    bf16x8 af[4];
    {
        int nodeA = load_node(segA, ltA);
        load_af(segA, ltA, nodeA, af);
    }
    int segB = 0, ltB = 0, nodeB = 0;
    if (ft0 + 1 < ft1) {
        resolve(ft0 + 1, segB, ltB);
        nodeB = load_node(segB, ltB);
    }

    for (int ft = ft0; ft < ft1; ++ft) {
        const int seg = segA, lt = ltA;
        const bool haveN  = (ft + 1 < ft1);
        const bool haveN2 = (ft + 2 < ft1);

        // stage 3: issue csrc for t+2 (completes during next iteration)
        int segC = 0, ltC = 0, nodeC = 0;
        if (haveN2) {
            resolve(ft + 2, segC, ltC);
            nodeC = load_node(segC, ltC);
        }

        // stage 2: issue XB gathers for t+1 (nodeB loaded one iteration ago)
        bf16x8 afn[4];
        if (haveN) load_af(segB, ltB, nodeB, afn);

        // (re)load B-frags + bias at segment boundary (<=2 per block)
        if (seg != cur_seg) {
            const unsigned short* Wseg = WT + (size_t)seg * D * D;
#pragma unroll
            for (int nt = 0; nt < 8; ++nt) {
                const unsigned short* bp = Wseg + (size_t)(nt * 16 + l16) * D + cq8;
#pragma unroll
                for (int kc = 0; kc < 4; ++kc)
                    bfr[nt][kc] = *(const bf16x8*)(bp + kc * 32);
                bv[nt] = (seg == 0) ? bias[nt * 16 + l16] : 0.f;
            }
            cur_seg = seg;
        }

        // stage 1: compute tile t (bias folded into MFMA C-in; same f32 math)
        f32x4 acc[8];
#pragma unroll
        for (int nt = 0; nt < 8; ++nt) {
            acc[nt] = (f32x4){bv[nt], bv[nt], bv[nt], bv[nt]};
#pragma unroll
            for (int kc = 0; kc < 4; ++kc)
                acc[nt] = __builtin_amdgcn_mfma_f32_16x16x32_bf16(
                    af[kc], bfr[nt][kc], acc[nt], 0, 0, 0);
        }

        // Epilogue: hardware RNE pack (col 32p+l16, col 32p+l16+16) -> u32,
        // one dwordx4 per owned row. Coalesces as 4x256B segments per inst.
        // (inline-asm cvt_pk is safe HERE: at (256,2) acc stays in VGPRs --
        //  passed three times. Do not reuse at (256,4).)
        {
            const int rbase = lt * 64 + wave * 16 + quad * 4;
            unsigned short* Hrow =
                H + (size_t)(s_base[seg] + rbase) * D + (size_t)l16 * 8;
#pragma unroll
            for (int reg = 0; reg < 4; ++reg) {
                if (rbase + reg < s_cnt[seg]) {
                    u32x4 w;
#pragma unroll
                    for (int p = 0; p < 4; ++p) {
                        unsigned r;
                        asm("v_cvt_pk_bf16_f32 %0, %1, %2"
                            : "=v"(r)
                            : "v"(acc[2 * p][reg]), "v"(acc[2 * p + 1][reg]));
                        w[p] = r;
                    }
                    *(u32x4*)(Hrow + (size_t)reg * D) = w;
                }
            }
        }

        // rotate pipeline state
        if (haveN) {
            segA = segB; ltA = ltB;
#pragma unroll
            for (int kc = 0; kc < 4; ++kc) af[kc] = afn[kc];
        }
        if (haveN2) { segB = segC; ltB = ltC; nodeB = nodeC; }
    }
}

// ---------------------------------------------------------------------------
// Phase 2: one wave per dst node; dst made explicitly wave-uniform so
// pk2/bounds go through scalar loads; per-lane work = H load + 2 unpack +
// 2 FMA per edge. Per-(dst,rel) counts via wave-parallel ballot histogram
// (one coalesced pk2 vector load, 8 ballots -> packed 8-bit fields in two
// u32s; scalar fallback for degree > 64). 1/c via v_rcp (~1 ulp).
// H columns are permuted (see gemm_h): lane j's u32 holds cols
// c0 = 32*(j&3) + (j>>2) and c0+16 -> two dword stores at the end.
// ---------------------------------------------------------------------------
__global__ __launch_bounds__(256) void gather_out(
    const unsigned short* __restrict__ H, const unsigned* __restrict__ pk2,
    const int* __restrict__ tmpd, const int* __restrict__ offsd,
    float* __restrict__ out, int n_nodes)
{
    int dst = (blockIdx.x * 256 + threadIdx.x) >> 6;
    const int lane = threadIdx.x & 63;
    if (dst >= n_nodes) return;
    dst = __builtin_amdgcn_readfirstlane(dst);   // wave-uniform by construction

    const unsigned* HH = (const unsigned*)H;
    unsigned u0 = HH[(size_t)dst * 64 + lane];   // root+bias row
    float a0 = bf_lo(u0), a1 = bf_hi(u0);

    const int e0 = tmpd[dst] + offsd[dst >> 10];
    const int e1 = tmpd[dst + 1] + offsd[(dst + 1) >> 10];
    const int d  = e1 - e0;

    // per-rel counts (8x 8-bit fields in two u32s)
    unsigned acc0 = 0, acc1 = 0;
    if (d <= 64) {
        const bool valid = lane < d;
        unsigned p = valid ? pk2[e0 + lane] : 0u;
        unsigned r = (p >> 20) & 7u;
#pragma unroll
        for (int rr = 0; rr < 8; ++rr) {
            unsigned long long m = __ballot(valid && (r == (unsigned)rr));
            unsigned cnt = (unsigned)__popcll(m);
            if (rr < 4) acc0 |= cnt << (rr * 8);
            else        acc1 |= cnt << ((rr - 4) * 8);
        }
    } else {
        for (int e = e0; e < e1; ++e) {
            unsigned p = pk2[e];
            unsigned r = (p >> 20) & 7u;
            unsigned add = 1u << ((r & 3u) * 8u);
            if (r & 4u) acc1 += add; else acc0 += add;
        }
    }

    for (int base = e0; base < e1; base += 8) {
        float al[8];
        const unsigned* hp[8];
#pragma unroll
        for (int j = 0; j < 8; ++j) {
            int e = base + j;
            bool ok = (e < e1);
            unsigned p = ok ? pk2[e] : 0u;       // uniform address -> s_load
            unsigned r = (p >> 20) & 7u;
            unsigned cnt = (((r & 4u) ? acc1 : acc0) >> ((r & 3u) * 8u)) & 255u;
            al[j] = ok ? __builtin_amdgcn_rcpf((float)cnt) : 0.f;
            hp[j] = HH + (size_t)(p & 0xFFFFFu) * 64;
        }
        unsigned hv[8];
#pragma unroll
        for (int j = 0; j < 8; ++j) hv[j] = hp[j][lane];
#pragma unroll
        for (int j = 0; j < 8; ++j) {
            a0 += al[j] * bf_lo(hv[j]);
            a1 += al[j] * bf_hi(hv[j]);
        }
    }

    const int c0 = ((lane & 3) << 5) + (lane >> 2);
    float* orow = out + (size_t)dst * D;
    orow[c0]      = fmaxf(a0, 0.f);
    orow[c0 + 16] = fmaxf(a1, 0.f);
}

extern "C" void kernel_launch(void* const* d_in, const int* in_sizes, int n_in,
                              void* d_out, int out_size, void* d_ws, size_t ws_size,
                              hipStream_t stream) {
    const float* x          = (const float*)d_in[0];
    const int*   edge_index = (const int*)d_in[1];
    const int*   edge_type  = (const int*)d_in[2];
    const float* W          = (const float*)d_in[3];
    const float* root       = (const float*)d_in[4];
    const float* bias       = (const float*)d_in[5];
    float* out = (float*)d_out;

    const int n_nodes = in_sizes[0] / D;          // 100000 (assumed %4==0)
    const int n_edges = in_sizes[2];              // 600000
    const int n_rel   = in_sizes[3] / (D * D);    // 8
    const int nsegs   = n_rel + 1;
    const int nwords  = (n_rel * n_nodes) >> 2;   // 200000 (800KB byte flags)

    // ws layout (worst-case compact rows = n_rel*n_nodes).
    // deg and flagsW are adjacent so ONE hipMemsetAsync zeroes both.
    char* p = (char*)d_ws;
    auto alloc = [&](size_t bytes) {
        char* q = p; p += (bytes + 255) & ~(size_t)255; return q;
    };
    int* deg    = (int*)alloc((size_t)(n_nodes + 2) * 4);
    unsigned* flagsW = (unsigned*)alloc((size_t)nwords * 4);
    int* tmpd   = (int*)alloc((size_t)(n_nodes + 2) * 4);
    int* tmpw   = (int*)alloc((size_t)(nwords + 1) * 4);
    int* partsd = (int*)alloc(4096);
    int* partsw = (int*)alloc(4096);
    int* offsd  = (int*)alloc(4096);
    int* offsw  = (int*)alloc(4096);
    int* totw   = (int*)alloc(256);
    int* erank  = (int*)alloc((size_t)n_edges * 4);
    unsigned* pk2 = (unsigned*)alloc((size_t)n_edges * 4);
    unsigned* XB  = (unsigned*)alloc((size_t)n_nodes * (D / 2) * 4);
    unsigned short* WT = (unsigned short*)alloc((size_t)nsegs * D * D * 2);
    int* csrc   = (int*)alloc((size_t)n_edges * 4);
    unsigned short* H = (unsigned short*)p;       // worst (n_nodes + n_edges) rows

    const int nquads   = n_nodes * (D / 4);
    const int wt_total = nsegs * D * D;
    int conv_n = nquads;
    if (wt_total > conv_n) conv_n = wt_total;

    const int egrid = (n_edges + 255) / 256;
    const int conv_blocks = (conv_n + 255) / 256;
    const int nAd = (n_nodes + 1 + 1023) / 1024;  // 98
    const int nAw = (nwords + 1023) / 1024;       // 196

    // zero deg + flagsW in one async memset (replaces the zero_ws kernel)
    size_t zlen = (size_t)((char*)(flagsW + nwords) - (char*)deg);
    hipMemsetAsync(deg, 0, zlen, stream);

    prep_hist<<<egrid + conv_blocks, 256, 0, stream>>>(
        x, W, root, edge_index, edge_type, XB, WT, deg,
        (unsigned char*)flagsW, erank,
        nquads, wt_total, n_edges, n_nodes, n_rel, egrid);
    scanA2<<<nAd + nAw, 1024, 0, stream>>>(
        deg, flagsW, tmpd, partsd, tmpw, partsw, n_nodes + 1, nwords, nAd);
    scanB2<<<2, 1024, 0, stream>>>(partsd, partsw, offsd, offsw, totw, nAd, nAw);
    edge_bin<<<egrid, 256, 0, stream>>>(
        edge_index, edge_type, tmpd, offsd, tmpw, offsw, flagsW, erank,
        pk2, csrc, n_edges, n_nodes, n_rel);
    gemm_h<<<512, 256, 0, stream>>>(
        XB, WT, bias, csrc, tmpw, offsw, totw, H, n_nodes, n_rel);
    gather_out<<<(n_nodes + 3) / 4, 256, 0, stream>>>(
        H, pk2, tmpd, offsd, out, n_nodes);
}